// Round 6
// baseline (701.077 us; speedup 1.0000x reference)
//
#include <hip/hip_runtime.h>
#include <hip/hip_fp16.h>

#define HIDDIM 256
#define NHEADS 8
#define UNR 8

struct half4 { __half2 a, b; };

// ---------------- GEMM: C[M,N] = act(A[M,K] @ W[K,N] + bias[N]) ----------------
// HALF_OUT=1 stores packed fp16 (N must be multiple of 64; columns aligned)
template <int HALF_OUT>
__global__ __launch_bounds__(256) void gemm_bias_act(
    const float* __restrict__ A, const float* __restrict__ W,
    const float* __restrict__ bias, void* __restrict__ Cv,
    int M, int N, int K, int act) {
  __shared__ float As[16][65];
  __shared__ float Bs[16][64];
  const int tid = threadIdx.x;
  const int bm = blockIdx.y * 64, bn = blockIdx.x * 64;
  const int tx = tid & 15, ty = tid >> 4;
  float acc[4][4] = {};
  for (int k0 = 0; k0 < K; k0 += 16) {
    {
      const int m = tid >> 2;
      const int k = (tid & 3) * 4;
      const int gm = bm + m;
      float4 v = make_float4(0.f, 0.f, 0.f, 0.f);
      if (gm < M) v = *(const float4*)(A + (size_t)gm * K + k0 + k);
      As[k + 0][m] = v.x; As[k + 1][m] = v.y; As[k + 2][m] = v.z; As[k + 3][m] = v.w;
    }
    {
      const int n = (tid & 15) * 4;
      const int k = tid >> 4;
      *(float4*)&Bs[k][n] = *(const float4*)(W + (size_t)(k0 + k) * N + bn + n);
    }
    __syncthreads();
    #pragma unroll
    for (int kk = 0; kk < 16; ++kk) {
      float a[4], b[4];
      #pragma unroll
      for (int i = 0; i < 4; ++i) a[i] = As[kk][ty * 4 + i];
      #pragma unroll
      for (int j = 0; j < 4; ++j) b[j] = Bs[kk][tx * 4 + j];
      #pragma unroll
      for (int i = 0; i < 4; ++i)
        #pragma unroll
        for (int j = 0; j < 4; ++j) acc[i][j] = fmaf(a[i], b[j], acc[i][j]);
    }
    __syncthreads();
  }
  #pragma unroll
  for (int i = 0; i < 4; ++i) {
    const int gm = bm + ty * 4 + i;
    if (gm >= M) continue;
    float v[4];
    #pragma unroll
    for (int j = 0; j < 4; ++j) {
      const int gn = bn + tx * 4 + j;
      v[j] = acc[i][j] + bias[gn];
      if (act == 1 && v[j] < 0.f) v[j] = 0.f;
    }
    if (HALF_OUT) {
      half4 hv;
      hv.a = __floats2half2_rn(v[0], v[1]);
      hv.b = __floats2half2_rn(v[2], v[3]);
      *(half4*)((__half*)Cv + (size_t)gm * N + bn + tx * 4) = hv;
    } else {
      *(float4*)((float*)Cv + (size_t)gm * N + bn + tx * 4) =
          make_float4(v[0], v[1], v[2], v[3]);
    }
  }
}

// ---------------- CSR build (by destination; stores SRC node id) ----------------
__global__ __launch_bounds__(256) void count_deg(
    const int* __restrict__ ei, int* __restrict__ deg, int E, int Nn) {
  const int t = blockIdx.x * blockDim.x + threadIdx.x;
  const int ET = E + Nn;
  if (t >= ET) return;
  const int dst = (t < E) ? ei[E + t] : (t - E);
  atomicAdd(&deg[dst], 1);
}

__global__ __launch_bounds__(1024) void scan_deg(
    const int* __restrict__ deg, int* __restrict__ rowptr, int Nn) {
  __shared__ int wsum[16];
  __shared__ int carry_s;
  const int tid = threadIdx.x;
  const int wid = tid >> 6, lane = tid & 63;
  if (tid == 0) { carry_s = 0; rowptr[0] = 0; }
  __syncthreads();
  for (int base = 0; base < Nn; base += 1024) {
    const int i = base + tid;
    int s = (i < Nn) ? deg[i] : 0;
    #pragma unroll
    for (int off = 1; off < 64; off <<= 1) {
      int t = __shfl_up(s, off);
      if (lane >= off) s += t;
    }
    if (lane == 63) wsum[wid] = s;
    __syncthreads();
    if (wid == 0 && lane < 16) {
      int ws = wsum[lane];
      #pragma unroll
      for (int off = 1; off < 16; off <<= 1) {
        int t = __shfl_up(ws, off);
        if (lane >= off) ws += t;
      }
      wsum[lane] = ws;
    }
    __syncthreads();
    const int prefix = (wid > 0 ? wsum[wid - 1] : 0) + carry_s;
    if (i < Nn) rowptr[i + 1] = s + prefix;
    __syncthreads();
    if (tid == 0) carry_s += wsum[15];
    __syncthreads();
  }
}

__global__ __launch_bounds__(256) void fill_csr(
    const int* __restrict__ ei, const int* __restrict__ rowptr,
    int* __restrict__ cursor, int* __restrict__ csr, int E, int Nn) {
  const int t = blockIdx.x * blockDim.x + threadIdx.x;
  const int ET = E + Nn;
  if (t >= ET) return;
  int src, dst;
  if (t < E) { src = ei[t]; dst = ei[E + t]; }
  else { src = t - E; dst = t - E; }
  const int pos = atomicAdd(&cursor[dst], 1);
  csr[rowptr[dst] + pos] = src;
}

// ---------------- fused single-pass GATv2 per-node kernel (fp16 xl rows) ----------------
// one wave per node; lane covers channels [4*lane,4*lane+4); head h = lane>>3
template <int MODE>
__global__ __launch_bounds__(256) void node_gat(
    const __half* __restrict__ xl, const float* __restrict__ xr,
    const int* __restrict__ rowptr, const int* __restrict__ csr,
    const float* __restrict__ att, const float* __restrict__ bias,
    const float* __restrict__ lng, const float* __restrict__ lnb,
    const int* __restrict__ batch, float* __restrict__ pooled,
    float* __restrict__ counts, float* __restrict__ outp, int Nn) {
  int n = (int)((blockIdx.x * (size_t)blockDim.x + threadIdx.x) >> 6);
  const int lane = threadIdx.x & 63;
  if (n >= Nn) return;
  n = __builtin_amdgcn_readfirstlane(n);
  const int r0 = rowptr[n], r1 = rowptr[n + 1];
  const int jm = r1 - 1;
  const half4* __restrict__ xlv = (const half4*)xl;
  const float4 xr4 = *(const float4*)(xr + (size_t)n * HIDDIM + lane * 4);
  const float4 at4 = *(const float4*)(att + lane * 4);

  float m = -1e30f, d = 0.f;
  float4 acc = make_float4(0.f, 0.f, 0.f, 0.f);

  for (int j0 = r0; j0 <= jm; j0 += UNR) {
    // UNR independent 8-byte row-slice gathers (tail clamps to last edge)
    half4 r[UNR];
    #pragma unroll
    for (int k = 0; k < UNR; ++k) {
      int j = j0 + k; j = j <= jm ? j : jm;
      r[k] = xlv[(size_t)csr[j] * (HIDDIM / 4) + lane];
    }
    float4 a[UNR];
    float s[UNR];
    #pragma unroll
    for (int k = 0; k < UNR; ++k) {
      const float2 f01 = __half22float2(r[k].a);
      const float2 f23 = __half22float2(r[k].b);
      a[k] = make_float4(f01.x, f01.y, f23.x, f23.y);
      float v, ss;
      v = a[k].x + xr4.x; v = v >= 0.f ? v : 0.2f * v; ss = v * at4.x;
      v = a[k].y + xr4.y; v = v >= 0.f ? v : 0.2f * v; ss = fmaf(v, at4.y, ss);
      v = a[k].z + xr4.z; v = v >= 0.f ? v : 0.2f * v; ss = fmaf(v, at4.z, ss);
      v = a[k].w + xr4.w; v = v >= 0.f ? v : 0.2f * v; ss = fmaf(v, at4.w, ss);
      s[k] = ss;
    }
    #pragma unroll
    for (int k = 0; k < UNR; ++k) {
      s[k] += __shfl_xor(s[k], 1);
      s[k] += __shfl_xor(s[k], 2);
      s[k] += __shfl_xor(s[k], 4);
      if (j0 + k > jm) s[k] = -1e30f;
    }
    float mb = m;
    #pragma unroll
    for (int k = 0; k < UNR; ++k) mb = fmaxf(mb, s[k]);
    const float scale = __expf(m - mb);
    float w[UNR];
    float dsum = 0.f;
    #pragma unroll
    for (int k = 0; k < UNR; ++k) { w[k] = __expf(s[k] - mb); dsum += w[k]; }
    d = fmaf(d, scale, dsum);
    float ax = acc.x * scale, ay = acc.y * scale, az = acc.z * scale, aw = acc.w * scale;
    #pragma unroll
    for (int k = 0; k < UNR; ++k) {
      ax = fmaf(w[k], a[k].x, ax);
      ay = fmaf(w[k], a[k].y, ay);
      az = fmaf(w[k], a[k].z, az);
      aw = fmaf(w[k], a[k].w, aw);
    }
    acc = make_float4(ax, ay, az, aw);
    m = mb;
  }
  const float inv_d = 1.f / d;

  // epilogue: bias + relu
  const float4 bb = *(const float4*)(bias + lane * 4);
  float t0 = fmaf(acc.x, inv_d, bb.x); t0 = t0 > 0.f ? t0 : 0.f;
  float t1 = fmaf(acc.y, inv_d, bb.y); t1 = t1 > 0.f ? t1 : 0.f;
  float t2 = fmaf(acc.z, inv_d, bb.z); t2 = t2 > 0.f ? t2 : 0.f;
  float t3 = fmaf(acc.w, inv_d, bb.w); t3 = t3 > 0.f ? t3 : 0.f;

  if (MODE == 0) {
    float s = t0 + t1 + t2 + t3;
    #pragma unroll
    for (int mm = 1; mm < 64; mm <<= 1) s += __shfl_xor(s, mm);
    const float mu = s * (1.f / HIDDIM);
    const float d0 = t0 - mu, d1 = t1 - mu, d2 = t2 - mu, d3 = t3 - mu;
    float q = d0 * d0 + d1 * d1 + d2 * d2 + d3 * d3;
    #pragma unroll
    for (int mm = 1; mm < 64; mm <<= 1) q += __shfl_xor(q, mm);
    const float inv = rsqrtf(q * (1.f / HIDDIM) + 1e-5f);
    const float4 g4 = *(const float4*)(lng + lane * 4);
    const float4 b4 = *(const float4*)(lnb + lane * 4);
    float4 o;
    o.x = d0 * inv * g4.x + b4.x;
    o.y = d1 * inv * g4.y + b4.y;
    o.z = d2 * inv * g4.z + b4.z;
    o.w = d3 * inv * g4.w + b4.w;
    *(float4*)(outp + (size_t)n * HIDDIM + lane * 4) = o;
  } else {
    const int g = batch[n];
    float* p = pooled + (size_t)g * HIDDIM + lane * 4;
    atomicAdd(p + 0, t0);
    atomicAdd(p + 1, t1);
    atomicAdd(p + 2, t2);
    atomicAdd(p + 3, t3);
    if (lane == 0) atomicAdd(&counts[g], 1.f);
  }
}

// ---------------- head MLP ----------------
__global__ __launch_bounds__(256) void head_kernel(
    const float* __restrict__ pooled, const float* __restrict__ counts,
    const float* __restrict__ h1w, const float* __restrict__ h1b,
    const float* __restrict__ h2w, const float* __restrict__ h2b,
    float* __restrict__ out, int G, int H1, int OUT) {
  __shared__ float P[16][HIDDIM];
  __shared__ float Hh[16][128];
  const int tid = threadIdx.x;
  for (int i = tid; i < G * HIDDIM; i += 256) {
    const int g = i / HIDDIM, c = i % HIDDIM;
    float cnt = counts[g];
    if (cnt < 1.f) cnt = 1.f;
    P[g][c] = pooled[i] / cnt;
  }
  __syncthreads();
  for (int i = tid; i < G * H1; i += 256) {
    const int g = i / H1, j = i % H1;
    float s = h1b[j];
    for (int k = 0; k < HIDDIM; ++k) s = fmaf(P[g][k], h1w[k * H1 + j], s);
    Hh[g][j] = s > 0.f ? s : 0.f;
  }
  __syncthreads();
  for (int i = tid; i < G * OUT; i += 256) {
    const int g = i / OUT, o = i % OUT;
    float s = h2b[o];
    for (int k = 0; k < H1; ++k) s = fmaf(Hh[g][k], h2w[k * OUT + o], s);
    out[i] = s;
  }
}

extern "C" void kernel_launch(void* const* d_in, const int* in_sizes, int n_in,
                              void* d_out, int out_size, void* d_ws, size_t ws_size,
                              hipStream_t stream) {
  const float* x = (const float*)d_in[0];
  const int* ei = (const int*)d_in[1];
  const int* batch = (const int*)d_in[2];
  const float* enc_w = (const float*)d_in[3];
  const float* enc_b = (const float*)d_in[4];
  const float* g_wl[2] = {(const float*)d_in[5], (const float*)d_in[11]};
  const float* g_bl[2] = {(const float*)d_in[6], (const float*)d_in[12]};
  const float* g_wr[2] = {(const float*)d_in[7], (const float*)d_in[13]};
  const float* g_br[2] = {(const float*)d_in[8], (const float*)d_in[14]};
  const float* g_att[2] = {(const float*)d_in[9], (const float*)d_in[15]};
  const float* g_bias[2] = {(const float*)d_in[10], (const float*)d_in[16]};
  const float* ln_g = (const float*)d_in[17];
  const float* ln_b = (const float*)d_in[18];
  const float* h1_w = (const float*)d_in[19];
  const float* h1_b = (const float*)d_in[20];
  const float* h2_w = (const float*)d_in[21];
  const float* h2_b = (const float*)d_in[22];
  float* out = (float*)d_out;

  const int N = in_sizes[2];          // 20000
  const int E = in_sizes[1] / 2;      // 320000
  const int DIN = in_sizes[0] / N;    // 128
  const int ET = E + N;
  const int H1 = in_sizes[20];        // 128
  const int OUT = in_sizes[22];       // 2
  const int G = out_size / OUT;       // 16

  float* ws = (float*)d_ws;
  const size_t NH = (size_t)N * HIDDIM;
  float* h0 = ws;
  float* xr = h0 + NH;
  __half* xl = (__half*)(xr + NH);                          // NH halves
  float* pooled = (float*)((char*)xl + NH * sizeof(__half));// [G,256]
  float* counts = pooled + (size_t)G * HIDDIM;              // [G]
  int* deg = (int*)(counts + G);                            // [N]
  int* rowptr = deg + N;                                    // [N+1]
  int* cursor = rowptr + (N + 1);                           // [N]
  int* csr = cursor + N;                                    // [ET]

  const dim3 blk(256);
  const dim3 gemm_grid(HIDDIM / 64, (N + 63) / 64);
  const int eb = (ET + 255) / 256;
  const int nb = (N + 3) / 4;

  // CSR build (graph identical for both layers)
  hipMemsetAsync(deg, 0, (size_t)N * sizeof(int), stream);
  hipMemsetAsync(cursor, 0, (size_t)N * sizeof(int), stream);
  hipMemsetAsync(pooled, 0, ((size_t)G * HIDDIM + G) * sizeof(float), stream);
  count_deg<<<eb, blk, 0, stream>>>(ei, deg, E, N);
  scan_deg<<<1, 1024, 0, stream>>>(deg, rowptr, N);
  fill_csr<<<eb, blk, 0, stream>>>(ei, rowptr, cursor, csr, E, N);

  // encoder
  gemm_bias_act<0><<<gemm_grid, blk, 0, stream>>>(x, enc_w, enc_b, h0, N, HIDDIM, DIN, 1);

  for (int L = 0; L < 2; ++L) {
    gemm_bias_act<1><<<gemm_grid, blk, 0, stream>>>(h0, g_wl[L], g_bl[L], xl, N, HIDDIM, HIDDIM, 0);
    gemm_bias_act<0><<<gemm_grid, blk, 0, stream>>>(h0, g_wr[L], g_br[L], xr, N, HIDDIM, HIDDIM, 0);
    if (L == 0) {
      node_gat<0><<<nb, blk, 0, stream>>>(xl, xr, rowptr, csr, g_att[0], g_bias[0],
                                          ln_g, ln_b, nullptr, nullptr, nullptr, h0, N);
    } else {
      node_gat<1><<<nb, blk, 0, stream>>>(xl, xr, rowptr, csr, g_att[1], g_bias[1],
                                          nullptr, nullptr, batch, pooled, counts, nullptr, N);
    }
  }
  head_kernel<<<1, blk, 0, stream>>>(pooled, counts, h1_w, h1_b, h2_w, h2_b, out, G, H1, OUT);
}